// Round 1
// 497.908 us; speedup vs baseline: 1.0279x; 1.0279x over previous
//
#include <hip/hip_runtime.h>
#include <math.h>

#define IN_DIM 256
#define HD 128
#define OUT_DIM 40
#define S2_STRIDE 64
#define NB_CS 1024  // colsum blocks in fuse1
#define NXCD 8

// physical XCD id (0..7), verified on gfx950 via s_getreg(HW_REG_XCC_ID)
__device__ __forceinline__ int xcc_id() {
    int x;
    asm volatile("s_getreg_b32 %0, hwreg(HW_REG_XCC_ID)" : "=s"(x));
    return x & (NXCD - 1);
}

// ---------------- init ----------------
__global__ __launch_bounds__(256) void k_init(int* deg8, float* muacc8, int N8) {
    int i = blockIdx.x * 256 + threadIdx.x;
    if (i < N8) deg8[i] = 0;
    if (i < NXCD * 256) muacc8[i] = 0.f;
}

// ---------------- fuse1: colsum (float4) + deg/rank + wprep ----------------
// deg counting: per-XCD replica counters, workgroup-scope atomics -> L2-local RMW
// rank[e] = (xcd << 28) | local_rank_within_(xcd,dst)
__global__ __launch_bounds__(256) void k_fuse1(const float* __restrict__ x, int N,
                                               float* __restrict__ muacc8,
                                               const int* __restrict__ ei, int E, int* deg8,
                                               int* __restrict__ rank, int ebl,
                                               const float* __restrict__ W0,
                                               const float* __restrict__ W1,
                                               const float* __restrict__ W2,
                                               unsigned long long* W0p,
                                               unsigned long long* W1p,
                                               unsigned long long* W2p,
                                               float* aS0, float* aS1, float* aS2) {
    __shared__ float lds[256];
    int b = blockIdx.x, tid = threadIdx.x;
    if (b < NB_CS) {                       // ---- colsum ----
        size_t F4 = (size_t)N * (IN_DIM / 4);
        size_t stride = (size_t)NB_CS * 256;
        float a0 = 0.f, a1 = 0.f, a2 = 0.f, a3 = 0.f;
        const float4* x4 = (const float4*)x;
        for (size_t i = (size_t)b * 256 + tid; i < F4; i += stride) {
            float4 v = x4[i];
            a0 += v.x; a1 += v.y; a2 += v.z; a3 += v.w;
        }
        lds[tid] = 0.f;
        __syncthreads();
        int c0 = (tid * 4) & 255;
        atomicAdd(&lds[c0], a0);
        atomicAdd(&lds[c0 + 1], a1);
        atomicAdd(&lds[c0 + 2], a2);
        atomicAdd(&lds[c0 + 3], a3);
        __syncthreads();
        int xc = xcc_id();
        __hip_atomic_fetch_add(&muacc8[xc * 256 + tid], lds[tid],
                               __ATOMIC_RELAXED, __HIP_MEMORY_SCOPE_WORKGROUP);
    } else if (b < NB_CS + ebl) {          // ---- deg + per-edge rank (L2-local) ----
        int e = (b - NB_CS) * 256 + tid;
        if (e < E) {
            int d = ei[E + e];
            int xc = xcc_id();
            int old = __hip_atomic_fetch_add(&deg8[(size_t)xc * N + d], 1,
                                             __ATOMIC_RELAXED, __HIP_MEMORY_SCOPE_WORKGROUP);
            rank[e] = old | (xc << 28);
        }
    } else {                               // ---- wprep ----
        int b2 = b - NB_CS - ebl;
        int lane = tid & 63, w = tid >> 6;
        if (b2 < 32) {                     // W0: [256,128]
            int j = b2 * 4 + w;
            float asum = 0.f;
            unsigned long long words[4];
            #pragma unroll
            for (int q = 0; q < 4; ++q) {
                float v = W0[(size_t)(4 * lane + q) * HD + j];
                asum += fabsf(v);
                words[q] = __ballot(v < 0.f);
            }
            #pragma unroll
            for (int off = 32; off; off >>= 1) asum += __shfl_xor(asum, off);
            if (lane == 0) {
                aS0[j] = 2.f * asum / 256.f;
                #pragma unroll
                for (int q = 0; q < 4; ++q) W0p[j * 4 + q] = words[q];
            }
        } else if (b2 < 64) {              // W1: [128,128]
            int j = (b2 - 32) * 4 + w;
            int fl = lane & 15, kk = lane >> 4;
            float asum = 0.f;
            unsigned long long words[2];
            #pragma unroll
            for (int q = 0; q < 2; ++q) {
                float v = W1[(size_t)(fl * 8 + 4 * q + kk) * HD + j];
                asum += fabsf(v);
                words[q] = __ballot(v < 0.f);
            }
            #pragma unroll
            for (int off = 32; off; off >>= 1) asum += __shfl_xor(asum, off);
            if (lane == 0) {
                aS1[j] = 2.f * asum / 128.f;
                W1p[j * 2 + 0] = words[0];
                W1p[j * 2 + 1] = words[1];
            }
        } else {                           // W2: [128,40]
            int j = (b2 - 64) * 4 + w;
            int fl = lane & 15, kk = lane >> 4;
            if (j < OUT_DIM) {
                float asum = 0.f;
                unsigned long long words[2];
                #pragma unroll
                for (int q = 0; q < 2; ++q) {
                    float v = W2[(size_t)(fl * 8 + 4 * q + kk) * OUT_DIM + j];
                    asum += fabsf(v);
                    words[q] = __ballot(v < 0.f);
                }
                #pragma unroll
                for (int off = 32; off; off >>= 1) asum += __shfl_xor(asum, off);
                if (lane == 0) {
                    aS2[j] = 2.f * asum / 128.f;
                    W2p[j * 2 + 0] = words[0];
                    W2p[j * 2 + 1] = words[1];
                }
            }
        }
    }
}

// ---------------- CSR build (small kernels) ----------------
// k_bp: reduce per-XCD deg replicas -> per-(xcd,node) exclusive offsets (xoff),
// total real-edge count (cnt), dinv; also per-block sum for CSR prefix.
__global__ __launch_bounds__(256) void k_bp(const int* __restrict__ deg8, int N, int* bp,
                                            int* __restrict__ xoff, float* __restrict__ dinv,
                                            int* __restrict__ cnt) {
    __shared__ int sm[256];
    int i = blockIdx.x * 256 + threadIdx.x;
    int c = 0;
    if (i < N) {
        int run = 0;
        #pragma unroll
        for (int xc = 0; xc < NXCD; ++xc) {
            int v = deg8[(size_t)xc * N + i];
            xoff[(size_t)xc * N + i] = run;
            run += v;
        }
        c = run;
        cnt[i] = run;
        dinv[i] = (float)(1.0 / sqrt((double)(run + 1)));   // +1 self loop
    }
    sm[threadIdx.x] = c;
    __syncthreads();
    for (int off = 128; off; off >>= 1) {
        if (threadIdx.x < off) sm[threadIdx.x] += sm[threadIdx.x + off];
        __syncthreads();
    }
    if (threadIdx.x == 0) bp[blockIdx.x] = sm[0];
}

__global__ __launch_bounds__(512) void k_scanbp(const int* __restrict__ bp, int NB, int* bps,
                                                const float* __restrict__ muacc8,
                                                float* __restrict__ mu) {
    __shared__ int sm[512];
    int t = threadIdx.x;
    if (t < 256) {                         // finalize column sums
        float s = 0.f;
        #pragma unroll
        for (int xc = 0; xc < NXCD; ++xc) s += muacc8[xc * 256 + t];
        mu[t] = s;
    }
    int v = (t < NB) ? bp[t] : 0;
    sm[t] = v;
    __syncthreads();
    for (int off = 1; off < 512; off <<= 1) {
        int add = (t >= off) ? sm[t - off] : 0;
        __syncthreads();
        sm[t] += add;
        __syncthreads();
    }
    if (t < NB) bps[t] = sm[t] - v;        // exclusive
}

__global__ __launch_bounds__(256) void k_rowptr(const int* __restrict__ cnt,
                                                const int* __restrict__ bps, int N, int E,
                                                int* row_ptr) {
    __shared__ int wsum[4];
    int t = threadIdx.x, lane = t & 63, w = t >> 6;
    int i = blockIdx.x * 256 + t;
    int c = (i < N) ? cnt[i] : 0;
    int v = c;
    #pragma unroll
    for (int off = 1; off < 64; off <<= 1) {
        int n = __shfl_up(v, off);
        if (lane >= off) v += n;
    }
    if (lane == 63) wsum[w] = v;
    __syncthreads();
    int wo = 0;
    for (int k = 0; k < w; ++k) wo += wsum[k];
    int excl = bps[blockIdx.x] + wo + v - c;
    if (i < N) row_ptr[i] = excl;
    if (blockIdx.x == 0 && t == 0) row_ptr[N] = E;
}

// ---------------- fuse2: atomic-free edge scatter + layer-0 matmul ----------------
__global__ __launch_bounds__(256) void k_fuse2(const int* __restrict__ ei, int E,
                                               const float* __restrict__ dinv,
                                               const int* __restrict__ rowp,
                                               const int* __restrict__ rank,
                                               const int* __restrict__ xoff,
                                               long long* __restrict__ cs, int nbScat,
                                               const float* __restrict__ x,
                                               const float* __restrict__ muacc, float inv_n,
                                               const unsigned long long* __restrict__ W0p,
                                               unsigned char* __restrict__ S0, int N) {
    __shared__ unsigned long long w0s[128 * 4];
    int b = blockIdx.x, tid = threadIdx.x;
    if (b < nbScat) {                      // ---- scatter (no atomics) ----
        int e = b * 256 + tid;
        if (e >= E) return;
        int s = ei[e];
        int d = ei[E + e];
        int r = rank[e];
        int xc = ((unsigned int)r) >> 28;
        int lr = r & 0x0FFFFFFF;
        int pos = rowp[d] + xoff[(size_t)xc * N + d] + lr;
        float nrm = dinv[s] * dinv[d];
        long long v = (long long)(unsigned int)s |
                      ((long long)(unsigned int)__float_as_int(nrm) << 32);
        __builtin_nontemporal_store(v, &cs[pos]);
    } else {                               // ---- x_mm0 ----
        w0s[tid] = W0p[tid];
        w0s[tid + 256] = W0p[tid + 256];
        __syncthreads();
        int lane = tid & 63;
        int row = (b - nbScat) * 4 + (tid >> 6);
        if (row >= N) return;
        float4 xv = ((const float4*)(x + (size_t)row * IN_DIM))[lane];
        float4 ms = ((const float4*)muacc)[lane];
        unsigned long long xw[4];
        xw[0] = __ballot(xv.x < ms.x * inv_n);
        xw[1] = __ballot(xv.y < ms.y * inv_n);
        xw[2] = __ballot(xv.z < ms.z * inv_n);
        xw[3] = __ballot(xv.w < ms.w * inv_n);
        unsigned int pack = 0;
        #pragma unroll
        for (int t2 = 0; t2 < 2; ++t2) {
            int j = 2 * lane + t2;
            const unsigned long long* wc = &w0s[j * 4];
            int dd = __popcll(xw[0] ^ wc[0]) + __popcll(xw[1] ^ wc[1]) +
                     __popcll(xw[2] ^ wc[2]) + __popcll(xw[3] ^ wc[3]);
            int S = IN_DIM - 2 * dd;   // even, [-256,256]
            int s8 = S >> 1;
            if (s8 > 127) s8 = 127;
            pack |= ((unsigned int)(s8 + 128) & 0xffu) << (8 * t2);
        }
        *(unsigned short*)(S0 + (size_t)row * HD + 2 * lane) = (unsigned short)pack;
    }
}

// ---------------- agg + binarize + fused next popcount matmul ----------------
template <int OUTC>
__global__ __launch_bounds__(256) void k_agg_mm(const unsigned char* __restrict__ Sin, // [N][128]
                                                const int* __restrict__ row_ptr,
                                                const long long* __restrict__ cs,
                                                const float* __restrict__ dinv,
                                                const float* __restrict__ alphaS,
                                                const float* __restrict__ bias,
                                                const unsigned long long* __restrict__ Wnp,
                                                unsigned char* __restrict__ Sout, int N) {
    __shared__ unsigned long long wsm[OUTC * 2];
    int tid = threadIdx.x;
    for (int i = tid; i < OUTC * 2; i += 256) wsm[i] = Wnp[i];
    __syncthreads();
    int lane = tid & 63;
    int d = blockIdx.x * 4 + (tid >> 6);
    if (d >= N) return;
    int sub = lane >> 4;       // edge slot 0..3
    int fl  = lane & 15;       // 8-byte feature group
    float acc[8];
    #pragma unroll
    for (int k = 0; k < 8; ++k) acc[k] = 0.f;
    if (sub == 0) {            // self loop
        float dv = dinv[d];
        float nrm = dv * dv;
        unsigned long long r = *(const unsigned long long*)(Sin + (size_t)d * HD + fl * 8);
        unsigned int lo = (unsigned int)r, hi = (unsigned int)(r >> 32);
        #pragma unroll
        for (int k = 0; k < 4; ++k) {
            acc[k]     = fmaf(nrm, (float)((lo >> (8 * k)) & 0xffu) - 128.f, acc[k]);
            acc[k + 4] = fmaf(nrm, (float)((hi >> (8 * k)) & 0xffu) - 128.f, acc[k + 4]);
        }
    }
    int e0 = row_ptr[d], e1 = row_ptr[d + 1];
    int e = e0 + sub;
    for (; e + 4 < e1; e += 8) {           // 2 edges per iteration
        long long pa = cs[e];
        long long pb = cs[e + 4];
        int sa = (int)(unsigned int)pa;
        int sb = (int)(unsigned int)pb;
        unsigned long long ra = *(const unsigned long long*)(Sin + (size_t)sa * HD + fl * 8);
        unsigned long long rb = *(const unsigned long long*)(Sin + (size_t)sb * HD + fl * 8);
        float na = __int_as_float((int)(pa >> 32));
        float nb = __int_as_float((int)(pb >> 32));
        unsigned int la = (unsigned int)ra, ha = (unsigned int)(ra >> 32);
        unsigned int lb = (unsigned int)rb, hb = (unsigned int)(rb >> 32);
        #pragma unroll
        for (int k = 0; k < 4; ++k) {
            acc[k]     = fmaf(na, (float)((la >> (8 * k)) & 0xffu) - 128.f, acc[k]);
            acc[k + 4] = fmaf(na, (float)((ha >> (8 * k)) & 0xffu) - 128.f, acc[k + 4]);
            acc[k]     = fmaf(nb, (float)((lb >> (8 * k)) & 0xffu) - 128.f, acc[k]);
            acc[k + 4] = fmaf(nb, (float)((hb >> (8 * k)) & 0xffu) - 128.f, acc[k + 4]);
        }
    }
    if (e < e1) {                          // tail
        long long p = cs[e];
        int s = (int)(unsigned int)p;
        float nrm = __int_as_float((int)(p >> 32));
        unsigned long long r = *(const unsigned long long*)(Sin + (size_t)s * HD + fl * 8);
        unsigned int lo = (unsigned int)r, hi = (unsigned int)(r >> 32);
        #pragma unroll
        for (int k = 0; k < 4; ++k) {
            acc[k]     = fmaf(nrm, (float)((lo >> (8 * k)) & 0xffu) - 128.f, acc[k]);
            acc[k + 4] = fmaf(nrm, (float)((hi >> (8 * k)) & 0xffu) - 128.f, acc[k + 4]);
        }
    }
    // reduce across the 4 slots (allreduce -> every lane has full acc)
    #pragma unroll
    for (int k = 0; k < 8; ++k) {
        acc[k] += __shfl_xor(acc[k], 16);
        acc[k] += __shfl_xor(acc[k], 32);
    }
    // activation sign bits: feature f = fl*8 + k
    unsigned int m8 = 0;
    #pragma unroll
    for (int k = 0; k < 8; ++k) {
        int f = fl * 8 + k;
        float v = alphaS[f] * acc[k] + bias[f];
        if (v < 0.f) m8 |= (1u << k);
    }
    // assemble 128-bit sign vector: word q=k>>2, bit (fl + 16*(k&3))
    unsigned long long x0 = 0, x1 = 0;
    #pragma unroll
    for (int k = 0; k < 4; ++k) {
        unsigned long long bk = __ballot((m8 >> k) & 1u);
        x0 |= (bk & 0xffffULL) << (16 * k);
    }
    #pragma unroll
    for (int k = 4; k < 8; ++k) {
        unsigned long long bk = __ballot((m8 >> k) & 1u);
        x1 |= (bk & 0xffffULL) << (16 * (k - 4));
    }
    if (OUTC == 128) {
        unsigned int pack = 0;
        #pragma unroll
        for (int t2 = 0; t2 < 2; ++t2) {
            int j = 2 * lane + t2;
            int dd = __popcll(x0 ^ wsm[j * 2]) + __popcll(x1 ^ wsm[j * 2 + 1]);
            int S = HD - 2 * dd;  // even, [-128,128]
            pack |= ((unsigned int)((S >> 1) + 128) & 0xffu) << (8 * t2);
        }
        *(unsigned short*)(Sout + (size_t)d * HD + 2 * lane) = (unsigned short)pack;
    } else {
        int p8 = 128;  // biased zero padding
        if (lane < OUTC) {
            int dd = __popcll(x0 ^ wsm[lane * 2]) + __popcll(x1 ^ wsm[lane * 2 + 1]);
            p8 = ((HD - 2 * dd) >> 1) + 128;
        }
        Sout[(size_t)d * S2_STRIDE + lane] = (unsigned char)p8;
    }
}

// ---------------- final agg + log_softmax ----------------
__global__ __launch_bounds__(256) void k_agg_out(const unsigned char* __restrict__ S2, // [N][64]
                                                 const int* __restrict__ row_ptr,
                                                 const long long* __restrict__ cs,
                                                 const float* __restrict__ dinv,
                                                 const float* __restrict__ alphaS2,
                                                 const float* __restrict__ b2,
                                                 float* __restrict__ out, int N) {
    int tid = threadIdx.x, lane = tid & 63;
    int d = blockIdx.x * 4 + (tid >> 6);
    if (d >= N) return;
    int sub = lane >> 4;
    int fl  = lane & 15;
    float acc[4] = {0.f, 0.f, 0.f, 0.f};
    if (sub == 0) {            // self loop
        float dv = dinv[d];
        float nrm = dv * dv;
        unsigned int r4 = *(const unsigned int*)(S2 + (size_t)d * S2_STRIDE + fl * 4);
        #pragma unroll
        for (int k = 0; k < 4; ++k)
            acc[k] = fmaf(nrm, (float)((r4 >> (8 * k)) & 0xffu) - 128.f, acc[k]);
    }
    int e0 = row_ptr[d], e1 = row_ptr[d + 1];
    int e = e0 + sub;
    for (; e + 4 < e1; e += 8) {
        long long pa = cs[e];
        long long pb = cs[e + 4];
        int sa = (int)(unsigned int)pa;
        int sb = (int)(unsigned int)pb;
        unsigned int ra = *(const unsigned int*)(S2 + (size_t)sa * S2_STRIDE + fl * 4);
        unsigned int rb = *(const unsigned int*)(S2 + (size_t)sb * S2_STRIDE + fl * 4);
        float na = __int_as_float((int)(pa >> 32));
        float nb = __int_as_float((int)(pb >> 32));
        #pragma unroll
        for (int k = 0; k < 4; ++k) {
            acc[k] = fmaf(na, (float)((ra >> (8 * k)) & 0xffu) - 128.f, acc[k]);
            acc[k] = fmaf(nb, (float)((rb >> (8 * k)) & 0xffu) - 128.f, acc[k]);
        }
    }
    if (e < e1) {
        long long p = cs[e];
        int s = (int)(unsigned int)p;
        float nrm = __int_as_float((int)(p >> 32));
        unsigned int r4 = *(const unsigned int*)(S2 + (size_t)s * S2_STRIDE + fl * 4);
        #pragma unroll
        for (int k = 0; k < 4; ++k)
            acc[k] = fmaf(nrm, (float)((r4 >> (8 * k)) & 0xffu) - 128.f, acc[k]);
    }
    #pragma unroll
    for (int k = 0; k < 4; ++k) {
        acc[k] += __shfl_xor(acc[k], 16);
        acc[k] += __shfl_xor(acc[k], 32);
    }
    float h[4];
    float mymax = -INFINITY;
    #pragma unroll
    for (int k = 0; k < 4; ++k) {
        int f = fl * 4 + k;
        h[k] = (f < OUT_DIM) ? (alphaS2[f] * acc[k] + b2[f]) : -INFINITY;
        mymax = fmaxf(mymax, h[k]);
    }
    #pragma unroll
    for (int off = 1; off < 16; off <<= 1) mymax = fmaxf(mymax, __shfl_xor(mymax, off));
    float s4 = 0.f;
    #pragma unroll
    for (int k = 0; k < 4; ++k) {
        if (fl * 4 + k < OUT_DIM) s4 += expf(h[k] - mymax);
    }
    #pragma unroll
    for (int off = 1; off < 16; off <<= 1) s4 += __shfl_xor(s4, off);
    float lse = mymax + logf(s4);
    if (sub == 0 && fl < OUT_DIM / 4) {
        float4 o;
        o.x = h[0] - lse; o.y = h[1] - lse; o.z = h[2] - lse; o.w = h[3] - lse;
        *(float4*)(out + (size_t)d * OUT_DIM + fl * 4) = o;
    }
}

// ---------------- launcher ----------------
extern "C" void kernel_launch(void* const* d_in, const int* in_sizes, int n_in,
                              void* d_out, int out_size, void* d_ws, size_t ws_size,
                              hipStream_t stream) {
    const float* x  = (const float*)d_in[0];
    const int*   ei = (const int*)d_in[1];
    const float* W0 = (const float*)d_in[2];
    const float* b0 = (const float*)d_in[3];
    const float* W1 = (const float*)d_in[4];
    const float* b1 = (const float*)d_in[5];
    const float* W2 = (const float*)d_in[6];
    const float* b2 = (const float*)d_in[7];
    float* out = (float*)d_out;

    int N = in_sizes[0] / IN_DIM;
    int E = in_sizes[1] / 2;

    char* ws = (char*)d_ws;
    size_t off = 0;
    auto alloc = [&](size_t bytes) -> void* {
        off = (off + 255) & ~(size_t)255;
        void* p = (void*)(ws + off);
        off += bytes;
        return p;
    };
    float* mu     = (float*)alloc(256 * 4);
    float* muacc8 = (float*)alloc(NXCD * 256 * 4);
    int*   deg8   = (int*)alloc((size_t)NXCD * N * 4);
    int*   xoff   = (int*)alloc((size_t)NXCD * N * 4);
    int*   cnt    = (int*)alloc((size_t)N * 4);
    float* dinv   = (float*)alloc((size_t)N * 4);
    int*   rowp   = (int*)alloc(((size_t)N + 1) * 4);
    int*   bp     = (int*)alloc(512 * 4);
    int*   bps    = (int*)alloc(512 * 4);
    int*   rank   = (int*)alloc((size_t)E * 4);
    long long* cs = (long long*)alloc((size_t)E * 8);
    unsigned char* S0 = (unsigned char*)alloc((size_t)N * HD);
    unsigned char* S1 = (unsigned char*)alloc((size_t)N * HD);
    unsigned char* S2 = (unsigned char*)alloc((size_t)N * S2_STRIDE);
    unsigned long long* W0p = (unsigned long long*)alloc(128 * 4 * 8);
    unsigned long long* W1p = (unsigned long long*)alloc(128 * 2 * 8);
    unsigned long long* W2p = (unsigned long long*)alloc(40 * 2 * 8);
    float* aS0 = (float*)alloc(128 * 4);
    float* aS1 = (float*)alloc(128 * 4);
    float* aS2 = (float*)alloc(40 * 4);

    int nb256 = (N + 255) / 256;
    int ebl = (E + 255) / 256;
    int N8 = NXCD * N;
    int nbInit = (N8 + 255) / 256;
    float inv_n = 1.0f / (float)N;

    k_init<<<dim3(nbInit), dim3(256), 0, stream>>>(deg8, muacc8, N8);
    k_fuse1<<<dim3(NB_CS + ebl + 74), dim3(256), 0, stream>>>(
        x, N, muacc8, ei, E, deg8, rank, ebl, W0, W1, W2, W0p, W1p, W2p, aS0, aS1, aS2);
    k_bp<<<dim3(nb256), dim3(256), 0, stream>>>(deg8, N, bp, xoff, dinv, cnt);
    k_scanbp<<<dim3(1), dim3(512), 0, stream>>>(bp, nb256, bps, muacc8, mu);
    k_rowptr<<<dim3(nb256), dim3(256), 0, stream>>>(cnt, bps, N, E, rowp);

    int nb4 = (N + 3) / 4;
    k_fuse2<<<dim3(ebl + nb4), dim3(256), 0, stream>>>(
        ei, E, dinv, rowp, rank, xoff, cs, ebl, x, mu, inv_n, W0p, S0, N);
    k_agg_mm<128><<<dim3(nb4), dim3(256), 0, stream>>>(S0, rowp, cs, dinv, aS0, b0, W1p, S1, N);
    k_agg_mm<40><<<dim3(nb4), dim3(256), 0, stream>>>(S1, rowp, cs, dinv, aS1, b1, W2p, S2, N);
    k_agg_out<<<dim3(nb4), dim3(256), 0, stream>>>(S2, rowp, cs, dinv, aS2, b2, out, N);
    (void)out_size; (void)ws_size; (void)n_in;
}

// Round 2
// 489.011 us; speedup vs baseline: 1.0466x; 1.0182x over previous
//
#include <hip/hip_runtime.h>
#include <math.h>

#define IN_DIM 256
#define HD 128
#define OUT_DIM 40
#define S2_STRIDE 64
#define NB_CS 1024  // colsum blocks in fuse1
#define NXCD 8

// physical XCD id (0..7), verified on gfx950 via s_getreg(HW_REG_XCC_ID)
__device__ __forceinline__ int xcc_id() {
    int x;
    asm volatile("s_getreg_b32 %0, hwreg(HW_REG_XCC_ID)" : "=s"(x));
    return x & (NXCD - 1);
}

// ---------------- init ----------------
__global__ __launch_bounds__(256) void k_init(unsigned* deg8b, float* muacc8, int NW8) {
    int i = blockIdx.x * 256 + threadIdx.x;
    if (i < NW8) deg8b[i] = 0u;
    if (i < NXCD * 256) muacc8[i] = 0.f;
}

// ---------------- fuse1: colsum (float4) + deg/rank + wprep ----------------
// deg counting: per-XCD replicas of BYTE counters (4 per word), workgroup-scope
// atomics -> RMW entirely inside the local XCD L2 (replica = ~100 KB).
// rank[e] = (xcd << 28) | local_rank (byte)
__global__ __launch_bounds__(256) void k_fuse1(const float* __restrict__ x, int N,
                                               float* __restrict__ muacc8,
                                               const int* __restrict__ ei, int E,
                                               unsigned* __restrict__ deg8b, int NW,
                                               int* __restrict__ rank, int ebl,
                                               const float* __restrict__ W0,
                                               const float* __restrict__ W1,
                                               const float* __restrict__ W2,
                                               unsigned long long* W0p,
                                               unsigned long long* W1p,
                                               unsigned long long* W2p,
                                               float* aS0, float* aS1, float* aS2) {
    __shared__ float lds[256];
    int b = blockIdx.x, tid = threadIdx.x;
    if (b < NB_CS) {                       // ---- colsum ----
        size_t F4 = (size_t)N * (IN_DIM / 4);
        size_t stride = (size_t)NB_CS * 256;
        float a0 = 0.f, a1 = 0.f, a2 = 0.f, a3 = 0.f;
        const float4* x4 = (const float4*)x;
        for (size_t i = (size_t)b * 256 + tid; i < F4; i += stride) {
            float4 v = x4[i];
            a0 += v.x; a1 += v.y; a2 += v.z; a3 += v.w;
        }
        lds[tid] = 0.f;
        __syncthreads();
        int c0 = (tid * 4) & 255;
        atomicAdd(&lds[c0], a0);
        atomicAdd(&lds[c0 + 1], a1);
        atomicAdd(&lds[c0 + 2], a2);
        atomicAdd(&lds[c0 + 3], a3);
        __syncthreads();
        int xc = xcc_id();
        __hip_atomic_fetch_add(&muacc8[xc * 256 + tid], lds[tid],
                               __ATOMIC_RELAXED, __HIP_MEMORY_SCOPE_WORKGROUP);
    } else if (b < NB_CS + ebl) {          // ---- deg + per-edge rank (L2-local bytes) ----
        int e = (b - NB_CS) * 256 + tid;
        if (e < E) {
            int d = ei[E + e];
            int xc = xcc_id();
            int sh = 8 * (d & 3);
            unsigned old = __hip_atomic_fetch_add(&deg8b[(size_t)xc * NW + (d >> 2)],
                                                  1u << sh,
                                                  __ATOMIC_RELAXED, __HIP_MEMORY_SCOPE_WORKGROUP);
            rank[e] = (int)((old >> sh) & 0xFFu) | (xc << 28);
        }
    } else {                               // ---- wprep ----
        int b2 = b - NB_CS - ebl;
        int lane = tid & 63, w = tid >> 6;
        if (b2 < 32) {                     // W0: [256,128]
            int j = b2 * 4 + w;
            float asum = 0.f;
            unsigned long long words[4];
            #pragma unroll
            for (int q = 0; q < 4; ++q) {
                float v = W0[(size_t)(4 * lane + q) * HD + j];
                asum += fabsf(v);
                words[q] = __ballot(v < 0.f);
            }
            #pragma unroll
            for (int off = 32; off; off >>= 1) asum += __shfl_xor(asum, off);
            if (lane == 0) {
                aS0[j] = 2.f * asum / 256.f;
                #pragma unroll
                for (int q = 0; q < 4; ++q) W0p[j * 4 + q] = words[q];
            }
        } else if (b2 < 64) {              // W1: [128,128]
            int j = (b2 - 32) * 4 + w;
            int fl = lane & 15, kk = lane >> 4;
            float asum = 0.f;
            unsigned long long words[2];
            #pragma unroll
            for (int q = 0; q < 2; ++q) {
                float v = W1[(size_t)(fl * 8 + 4 * q + kk) * HD + j];
                asum += fabsf(v);
                words[q] = __ballot(v < 0.f);
            }
            #pragma unroll
            for (int off = 32; off; off >>= 1) asum += __shfl_xor(asum, off);
            if (lane == 0) {
                aS1[j] = 2.f * asum / 128.f;
                W1p[j * 2 + 0] = words[0];
                W1p[j * 2 + 1] = words[1];
            }
        } else {                           // W2: [128,40]
            int j = (b2 - 64) * 4 + w;
            int fl = lane & 15, kk = lane >> 4;
            if (j < OUT_DIM) {
                float asum = 0.f;
                unsigned long long words[2];
                #pragma unroll
                for (int q = 0; q < 2; ++q) {
                    float v = W2[(size_t)(fl * 8 + 4 * q + kk) * OUT_DIM + j];
                    asum += fabsf(v);
                    words[q] = __ballot(v < 0.f);
                }
                #pragma unroll
                for (int off = 32; off; off >>= 1) asum += __shfl_xor(asum, off);
                if (lane == 0) {
                    aS2[j] = 2.f * asum / 128.f;
                    W2p[j * 2 + 0] = words[0];
                    W2p[j * 2 + 1] = words[1];
                }
            }
        }
    }
}

// ---------------- CSR build (small kernels) ----------------
// k_bp: reduce per-XCD byte counters -> packed per-(xcd,node) exclusive byte
// offsets (xoffp, one u64/node), total count (cnt), dinv; per-block sums for CSR.
__global__ __launch_bounds__(256) void k_bp(const unsigned* __restrict__ deg8b, int NW, int N,
                                            int* bp, unsigned long long* __restrict__ xoffp,
                                            float* __restrict__ dinv, int* __restrict__ cnt) {
    __shared__ int sm[256];
    int i = blockIdx.x * 256 + threadIdx.x;
    int c = 0;
    if (i < N) {
        int w = i >> 2, sh = 8 * (i & 3);
        int run = 0;
        unsigned long long pack = 0;
        #pragma unroll
        for (int xc = 0; xc < NXCD; ++xc) {
            unsigned bc = (deg8b[(size_t)xc * NW + w] >> sh) & 0xFFu;
            pack |= (unsigned long long)(unsigned)run << (8 * xc);
            run += (int)bc;
        }
        xoffp[i] = pack;
        c = run;
        cnt[i] = run;
        dinv[i] = (float)(1.0 / sqrt((double)(run + 1)));   // +1 self loop
    }
    sm[threadIdx.x] = c;
    __syncthreads();
    for (int off = 128; off; off >>= 1) {
        if (threadIdx.x < off) sm[threadIdx.x] += sm[threadIdx.x + off];
        __syncthreads();
    }
    if (threadIdx.x == 0) bp[blockIdx.x] = sm[0];
}

__global__ __launch_bounds__(512) void k_scanbp(const int* __restrict__ bp, int NB, int* bps,
                                                const float* __restrict__ muacc8,
                                                float* __restrict__ mu) {
    __shared__ int sm[512];
    int t = threadIdx.x;
    if (t < 256) {                         // finalize column sums
        float s = 0.f;
        #pragma unroll
        for (int xc = 0; xc < NXCD; ++xc) s += muacc8[xc * 256 + t];
        mu[t] = s;
    }
    int v = (t < NB) ? bp[t] : 0;
    sm[t] = v;
    __syncthreads();
    for (int off = 1; off < 512; off <<= 1) {
        int add = (t >= off) ? sm[t - off] : 0;
        __syncthreads();
        sm[t] += add;
        __syncthreads();
    }
    if (t < NB) bps[t] = sm[t] - v;        // exclusive
}

__global__ __launch_bounds__(256) void k_rowptr(const int* __restrict__ cnt,
                                                const int* __restrict__ bps, int N, int E,
                                                int* row_ptr) {
    __shared__ int wsum[4];
    int t = threadIdx.x, lane = t & 63, w = t >> 6;
    int i = blockIdx.x * 256 + t;
    int c = (i < N) ? cnt[i] : 0;
    int v = c;
    #pragma unroll
    for (int off = 1; off < 64; off <<= 1) {
        int n = __shfl_up(v, off);
        if (lane >= off) v += n;
    }
    if (lane == 63) wsum[w] = v;
    __syncthreads();
    int wo = 0;
    for (int k = 0; k < w; ++k) wo += wsum[k];
    int excl = bps[blockIdx.x] + wo + v - c;
    if (i < N) row_ptr[i] = excl;
    if (blockIdx.x == 0 && t == 0) row_ptr[N] = E;
}

// ---------------- fuse2: atomic-free edge scatter + layer-0 matmul ----------------
// cs4[pos] = src index only (4B); norm recomputed in agg from dinv (L2-resident).
// w0s uses stride-9 ulonglong groups to break the 64B/lane LDS bank pattern.
__global__ __launch_bounds__(256) void k_fuse2(const int* __restrict__ ei, int E,
                                               const int* __restrict__ rowp,
                                               const int* __restrict__ rank,
                                               const unsigned long long* __restrict__ xoffp,
                                               int* __restrict__ cs4, int nbScat,
                                               const float* __restrict__ x,
                                               const float* __restrict__ muacc, float inv_n,
                                               const unsigned long long* __restrict__ W0p,
                                               unsigned char* __restrict__ S0, int N) {
    __shared__ unsigned long long w0s[576];  // 512 words + stride-9 padding
    int b = blockIdx.x, tid = threadIdx.x;
    if (b < nbScat) {                      // ---- scatter (no atomics) ----
        int e = b * 256 + tid;
        if (e >= E) return;
        int s = ei[e];
        int d = ei[E + e];
        unsigned r = (unsigned)rank[e];
        int xc = (int)(r >> 28);
        int lr = (int)(r & 0xFFu);
        int xo = (int)((xoffp[d] >> (8 * xc)) & 0xFFu);
        int pos = rowp[d] + xo + lr;
        __builtin_nontemporal_store(s, &cs4[pos]);
    } else {                               // ---- x_mm0 ----
        {
            int i = tid;
            w0s[9 * (i >> 3) + (i & 7)] = W0p[i];
            i = tid + 256;
            w0s[9 * (i >> 3) + (i & 7)] = W0p[i];
        }
        __syncthreads();
        int lane = tid & 63;
        int row = (b - nbScat) * 4 + (tid >> 6);
        if (row >= N) return;
        float4 xv = ((const float4*)(x + (size_t)row * IN_DIM))[lane];
        float4 ms = ((const float4*)muacc)[lane];
        unsigned long long xw[4];
        xw[0] = __ballot(xv.x < ms.x * inv_n);
        xw[1] = __ballot(xv.y < ms.y * inv_n);
        xw[2] = __ballot(xv.z < ms.z * inv_n);
        xw[3] = __ballot(xv.w < ms.w * inv_n);
        unsigned int pack = 0;
        #pragma unroll
        for (int t2 = 0; t2 < 2; ++t2) {
            // global word i = 8*lane + 4*t2 + q  ->  phys 9*lane + 4*t2 + q
            const unsigned long long* wc = &w0s[9 * lane + 4 * t2];
            int dd = __popcll(xw[0] ^ wc[0]) + __popcll(xw[1] ^ wc[1]) +
                     __popcll(xw[2] ^ wc[2]) + __popcll(xw[3] ^ wc[3]);
            int S = IN_DIM - 2 * dd;   // even, [-256,256]
            int s8 = S >> 1;
            if (s8 > 127) s8 = 127;
            pack |= ((unsigned int)(s8 + 128) & 0xffu) << (8 * t2);
        }
        *(unsigned short*)(S0 + (size_t)row * HD + 2 * lane) = (unsigned short)pack;
    }
}

// ---------------- agg + binarize + fused next popcount matmul ----------------
// wave = 1 dst; 4 slots x 16 lanes; lane loads 8B; edges batched 4 deep.
template <int OUTC>
__global__ __launch_bounds__(256) void k_agg_mm(const unsigned char* __restrict__ Sin, // [N][128]
                                                const int* __restrict__ row_ptr,
                                                const int* __restrict__ cs4,
                                                const float* __restrict__ dinv,
                                                const float* __restrict__ alphaS,
                                                const float* __restrict__ bias,
                                                const unsigned long long* __restrict__ Wnp,
                                                unsigned char* __restrict__ Sout, int N) {
    __shared__ unsigned long long wsm[OUTC * 2 + OUTC / 4 + 8];  // stride-9 swizzled
    int tid = threadIdx.x;
    for (int i = tid; i < OUTC * 2; i += 256) wsm[9 * (i >> 3) + (i & 7)] = Wnp[i];
    __syncthreads();
    int lane = tid & 63;
    int d = blockIdx.x * 4 + (tid >> 6);
    if (d >= N) return;
    int sub = lane >> 4;       // edge slot 0..3
    int fl  = lane & 15;       // 8-byte feature group
    float dv = dinv[d];
    float acc[8];
    #pragma unroll
    for (int k = 0; k < 8; ++k) acc[k] = 0.f;
    if (sub == 0) {            // self loop
        float nrm = dv * dv;
        unsigned long long r = *(const unsigned long long*)(Sin + (size_t)d * HD + fl * 8);
        unsigned int lo = (unsigned int)r, hi = (unsigned int)(r >> 32);
        #pragma unroll
        for (int k = 0; k < 4; ++k) {
            acc[k]     = fmaf(nrm, (float)((lo >> (8 * k)) & 0xffu) - 128.f, acc[k]);
            acc[k + 4] = fmaf(nrm, (float)((hi >> (8 * k)) & 0xffu) - 128.f, acc[k + 4]);
        }
    }
    int e0 = row_ptr[d], e1 = row_ptr[d + 1];
    int e = e0 + sub;
    for (; e + 12 < e1; e += 16) {         // 4 edges in flight
        int s0_ = cs4[e], s1_ = cs4[e + 4], s2_ = cs4[e + 8], s3_ = cs4[e + 12];
        float n0 = dinv[s0_] * dv, n1 = dinv[s1_] * dv;
        float n2 = dinv[s2_] * dv, n3 = dinv[s3_] * dv;
        unsigned long long r0 = *(const unsigned long long*)(Sin + (size_t)s0_ * HD + fl * 8);
        unsigned long long r1 = *(const unsigned long long*)(Sin + (size_t)s1_ * HD + fl * 8);
        unsigned long long r2 = *(const unsigned long long*)(Sin + (size_t)s2_ * HD + fl * 8);
        unsigned long long r3 = *(const unsigned long long*)(Sin + (size_t)s3_ * HD + fl * 8);
        #pragma unroll
        for (int k = 0; k < 4; ++k) {
            acc[k]     = fmaf(n0, (float)(((unsigned int)r0 >> (8 * k)) & 0xffu) - 128.f, acc[k]);
            acc[k + 4] = fmaf(n0, (float)(((unsigned int)(r0 >> 32) >> (8 * k)) & 0xffu) - 128.f, acc[k + 4]);
            acc[k]     = fmaf(n1, (float)(((unsigned int)r1 >> (8 * k)) & 0xffu) - 128.f, acc[k]);
            acc[k + 4] = fmaf(n1, (float)(((unsigned int)(r1 >> 32) >> (8 * k)) & 0xffu) - 128.f, acc[k + 4]);
            acc[k]     = fmaf(n2, (float)(((unsigned int)r2 >> (8 * k)) & 0xffu) - 128.f, acc[k]);
            acc[k + 4] = fmaf(n2, (float)(((unsigned int)(r2 >> 32) >> (8 * k)) & 0xffu) - 128.f, acc[k + 4]);
            acc[k]     = fmaf(n3, (float)(((unsigned int)r3 >> (8 * k)) & 0xffu) - 128.f, acc[k]);
            acc[k + 4] = fmaf(n3, (float)(((unsigned int)(r3 >> 32) >> (8 * k)) & 0xffu) - 128.f, acc[k + 4]);
        }
    }
    for (; e + 4 < e1; e += 8) {           // 2 edges
        int sa = cs4[e], sb = cs4[e + 4];
        float na = dinv[sa] * dv, nb = dinv[sb] * dv;
        unsigned long long ra = *(const unsigned long long*)(Sin + (size_t)sa * HD + fl * 8);
        unsigned long long rb = *(const unsigned long long*)(Sin + (size_t)sb * HD + fl * 8);
        unsigned int la = (unsigned int)ra, ha = (unsigned int)(ra >> 32);
        unsigned int lb = (unsigned int)rb, hb = (unsigned int)(rb >> 32);
        #pragma unroll
        for (int k = 0; k < 4; ++k) {
            acc[k]     = fmaf(na, (float)((la >> (8 * k)) & 0xffu) - 128.f, acc[k]);
            acc[k + 4] = fmaf(na, (float)((ha >> (8 * k)) & 0xffu) - 128.f, acc[k + 4]);
            acc[k]     = fmaf(nb, (float)((lb >> (8 * k)) & 0xffu) - 128.f, acc[k]);
            acc[k + 4] = fmaf(nb, (float)((hb >> (8 * k)) & 0xffu) - 128.f, acc[k + 4]);
        }
    }
    if (e < e1) {                          // tail
        int s = cs4[e];
        float nrm = dinv[s] * dv;
        unsigned long long r = *(const unsigned long long*)(Sin + (size_t)s * HD + fl * 8);
        unsigned int lo = (unsigned int)r, hi = (unsigned int)(r >> 32);
        #pragma unroll
        for (int k = 0; k < 4; ++k) {
            acc[k]     = fmaf(nrm, (float)((lo >> (8 * k)) & 0xffu) - 128.f, acc[k]);
            acc[k + 4] = fmaf(nrm, (float)((hi >> (8 * k)) & 0xffu) - 128.f, acc[k + 4]);
        }
    }
    // reduce across the 4 slots (allreduce -> every lane has full acc)
    #pragma unroll
    for (int k = 0; k < 8; ++k) {
        acc[k] += __shfl_xor(acc[k], 16);
        acc[k] += __shfl_xor(acc[k], 32);
    }
    // activation sign bits: feature f = fl*8 + k
    unsigned int m8 = 0;
    #pragma unroll
    for (int k = 0; k < 8; ++k) {
        int f = fl * 8 + k;
        float v = alphaS[f] * acc[k] + bias[f];
        if (v < 0.f) m8 |= (1u << k);
    }
    // assemble 128-bit sign vector: word q=k>>2, bit (fl + 16*(k&3))
    unsigned long long x0 = 0, x1 = 0;
    #pragma unroll
    for (int k = 0; k < 4; ++k) {
        unsigned long long bk = __ballot((m8 >> k) & 1u);
        x0 |= (bk & 0xffffULL) << (16 * k);
    }
    #pragma unroll
    for (int k = 4; k < 8; ++k) {
        unsigned long long bk = __ballot((m8 >> k) & 1u);
        x1 |= (bk & 0xffffULL) << (16 * (k - 4));
    }
    if (OUTC == 128) {
        unsigned int pack = 0;
        #pragma unroll
        for (int t2 = 0; t2 < 2; ++t2) {
            int j = 2 * lane + t2;
            int i0 = j * 2;
            const unsigned long long* wc = &wsm[9 * (i0 >> 3) + (i0 & 7)];
            int dd = __popcll(x0 ^ wc[0]) + __popcll(x1 ^ wc[1]);
            int S = HD - 2 * dd;  // even, [-128,128]
            pack |= ((unsigned int)((S >> 1) + 128) & 0xffu) << (8 * t2);
        }
        *(unsigned short*)(Sout + (size_t)d * HD + 2 * lane) = (unsigned short)pack;
    } else {
        int p8 = 128;  // biased zero padding
        if (lane < OUTC) {
            int i0 = lane * 2;
            const unsigned long long* wc = &wsm[9 * (i0 >> 3) + (i0 & 7)];
            int dd = __popcll(x0 ^ wc[0]) + __popcll(x1 ^ wc[1]);
            p8 = ((HD - 2 * dd) >> 1) + 128;
        }
        Sout[(size_t)d * S2_STRIDE + lane] = (unsigned char)p8;
    }
}

// ---------------- final agg + log_softmax ----------------
__global__ __launch_bounds__(256) void k_agg_out(const unsigned char* __restrict__ S2, // [N][64]
                                                 const int* __restrict__ row_ptr,
                                                 const int* __restrict__ cs4,
                                                 const float* __restrict__ dinv,
                                                 const float* __restrict__ alphaS2,
                                                 const float* __restrict__ b2,
                                                 float* __restrict__ out, int N) {
    int tid = threadIdx.x, lane = tid & 63;
    int d = blockIdx.x * 4 + (tid >> 6);
    if (d >= N) return;
    int sub = lane >> 4;
    int fl  = lane & 15;
    float dv = dinv[d];
    float acc[4] = {0.f, 0.f, 0.f, 0.f};
    if (sub == 0) {            // self loop
        float nrm = dv * dv;
        unsigned int r4 = *(const unsigned int*)(S2 + (size_t)d * S2_STRIDE + fl * 4);
        #pragma unroll
        for (int k = 0; k < 4; ++k)
            acc[k] = fmaf(nrm, (float)((r4 >> (8 * k)) & 0xffu) - 128.f, acc[k]);
    }
    int e0 = row_ptr[d], e1 = row_ptr[d + 1];
    int e = e0 + sub;
    for (; e + 12 < e1; e += 16) {         // 4 edges in flight
        int s0_ = cs4[e], s1_ = cs4[e + 4], s2_ = cs4[e + 8], s3_ = cs4[e + 12];
        float n0 = dinv[s0_] * dv, n1 = dinv[s1_] * dv;
        float n2 = dinv[s2_] * dv, n3 = dinv[s3_] * dv;
        unsigned int r0 = *(const unsigned int*)(S2 + (size_t)s0_ * S2_STRIDE + fl * 4);
        unsigned int r1 = *(const unsigned int*)(S2 + (size_t)s1_ * S2_STRIDE + fl * 4);
        unsigned int r2 = *(const unsigned int*)(S2 + (size_t)s2_ * S2_STRIDE + fl * 4);
        unsigned int r3 = *(const unsigned int*)(S2 + (size_t)s3_ * S2_STRIDE + fl * 4);
        #pragma unroll
        for (int k = 0; k < 4; ++k) {
            acc[k] = fmaf(n0, (float)((r0 >> (8 * k)) & 0xffu) - 128.f, acc[k]);
            acc[k] = fmaf(n1, (float)((r1 >> (8 * k)) & 0xffu) - 128.f, acc[k]);
            acc[k] = fmaf(n2, (float)((r2 >> (8 * k)) & 0xffu) - 128.f, acc[k]);
            acc[k] = fmaf(n3, (float)((r3 >> (8 * k)) & 0xffu) - 128.f, acc[k]);
        }
    }
    for (; e + 4 < e1; e += 8) {
        int sa = cs4[e], sb = cs4[e + 4];
        float na = dinv[sa] * dv, nb = dinv[sb] * dv;
        unsigned int ra = *(const unsigned int*)(S2 + (size_t)sa * S2_STRIDE + fl * 4);
        unsigned int rb = *(const unsigned int*)(S2 + (size_t)sb * S2_STRIDE + fl * 4);
        #pragma unroll
        for (int k = 0; k < 4; ++k) {
            acc[k] = fmaf(na, (float)((ra >> (8 * k)) & 0xffu) - 128.f, acc[k]);
            acc[k] = fmaf(nb, (float)((rb >> (8 * k)) & 0xffu) - 128.f, acc[k]);
        }
    }
    if (e < e1) {
        int s = cs4[e];
        float nrm = dinv[s] * dv;
        unsigned int r4 = *(const unsigned int*)(S2 + (size_t)s * S2_STRIDE + fl * 4);
        #pragma unroll
        for (int k = 0; k < 4; ++k)
            acc[k] = fmaf(nrm, (float)((r4 >> (8 * k)) & 0xffu) - 128.f, acc[k]);
    }
    #pragma unroll
    for (int k = 0; k < 4; ++k) {
        acc[k] += __shfl_xor(acc[k], 16);
        acc[k] += __shfl_xor(acc[k], 32);
    }
    float h[4];
    float mymax = -INFINITY;
    #pragma unroll
    for (int k = 0; k < 4; ++k) {
        int f = fl * 4 + k;
        h[k] = (f < OUT_DIM) ? (alphaS2[f] * acc[k] + b2[f]) : -INFINITY;
        mymax = fmaxf(mymax, h[k]);
    }
    #pragma unroll
    for (int off = 1; off < 16; off <<= 1) mymax = fmaxf(mymax, __shfl_xor(mymax, off));
    float s4 = 0.f;
    #pragma unroll
    for (int k = 0; k < 4; ++k) {
        if (fl * 4 + k < OUT_DIM) s4 += expf(h[k] - mymax);
    }
    #pragma unroll
    for (int off = 1; off < 16; off <<= 1) s4 += __shfl_xor(s4, off);
    float lse = mymax + logf(s4);
    if (sub == 0 && fl < OUT_DIM / 4) {
        float4 o;
        o.x = h[0] - lse; o.y = h[1] - lse; o.z = h[2] - lse; o.w = h[3] - lse;
        *(float4*)(out + (size_t)d * OUT_DIM + fl * 4) = o;
    }
}

// ---------------- launcher ----------------
extern "C" void kernel_launch(void* const* d_in, const int* in_sizes, int n_in,
                              void* d_out, int out_size, void* d_ws, size_t ws_size,
                              hipStream_t stream) {
    const float* x  = (const float*)d_in[0];
    const int*   ei = (const int*)d_in[1];
    const float* W0 = (const float*)d_in[2];
    const float* b0 = (const float*)d_in[3];
    const float* W1 = (const float*)d_in[4];
    const float* b1 = (const float*)d_in[5];
    const float* W2 = (const float*)d_in[6];
    const float* b2 = (const float*)d_in[7];
    float* out = (float*)d_out;

    int N = in_sizes[0] / IN_DIM;
    int E = in_sizes[1] / 2;
    int NW = (N + 3) / 4;       // words per byte-counter replica

    char* ws = (char*)d_ws;
    size_t off = 0;
    auto alloc = [&](size_t bytes) -> void* {
        off = (off + 255) & ~(size_t)255;
        void* p = (void*)(ws + off);
        off += bytes;
        return p;
    };
    float* mu     = (float*)alloc(256 * 4);
    float* muacc8 = (float*)alloc(NXCD * 256 * 4);
    unsigned* deg8b = (unsigned*)alloc((size_t)NXCD * NW * 4);
    unsigned long long* xoffp = (unsigned long long*)alloc((size_t)N * 8);
    int*   cnt    = (int*)alloc((size_t)N * 4);
    float* dinv   = (float*)alloc((size_t)N * 4);
    int*   rowp   = (int*)alloc(((size_t)N + 1) * 4);
    int*   bp     = (int*)alloc(512 * 4);
    int*   bps    = (int*)alloc(512 * 4);
    int*   rank   = (int*)alloc((size_t)E * 4);
    int*   cs4    = (int*)alloc((size_t)E * 4);
    unsigned char* S0 = (unsigned char*)alloc((size_t)N * HD);
    unsigned char* S1 = (unsigned char*)alloc((size_t)N * HD);
    unsigned char* S2 = (unsigned char*)alloc((size_t)N * S2_STRIDE);
    unsigned long long* W0p = (unsigned long long*)alloc(128 * 4 * 8);
    unsigned long long* W1p = (unsigned long long*)alloc(128 * 2 * 8);
    unsigned long long* W2p = (unsigned long long*)alloc(40 * 2 * 8);
    float* aS0 = (float*)alloc(128 * 4);
    float* aS1 = (float*)alloc(128 * 4);
    float* aS2 = (float*)alloc(40 * 4);

    int nb256 = (N + 255) / 256;
    int ebl = (E + 255) / 256;
    int NW8 = NXCD * NW;
    int nbInit = (NW8 + 255) / 256;
    float inv_n = 1.0f / (float)N;

    k_init<<<dim3(nbInit), dim3(256), 0, stream>>>(deg8b, muacc8, NW8);
    k_fuse1<<<dim3(NB_CS + ebl + 74), dim3(256), 0, stream>>>(
        x, N, muacc8, ei, E, deg8b, NW, rank, ebl, W0, W1, W2, W0p, W1p, W2p, aS0, aS1, aS2);
    k_bp<<<dim3(nb256), dim3(256), 0, stream>>>(deg8b, NW, N, bp, xoffp, dinv, cnt);
    k_scanbp<<<dim3(1), dim3(512), 0, stream>>>(bp, nb256, bps, muacc8, mu);
    k_rowptr<<<dim3(nb256), dim3(256), 0, stream>>>(cnt, bps, N, E, rowp);

    int nb4 = (N + 3) / 4;
    k_fuse2<<<dim3(ebl + nb4), dim3(256), 0, stream>>>(
        ei, E, rowp, rank, xoffp, cs4, ebl, x, mu, inv_n, W0p, S0, N);
    k_agg_mm<128><<<dim3(nb4), dim3(256), 0, stream>>>(S0, rowp, cs4, dinv, aS0, b0, W1p, S1, N);
    k_agg_mm<40><<<dim3(nb4), dim3(256), 0, stream>>>(S1, rowp, cs4, dinv, aS1, b1, W2p, S2, N);
    k_agg_out<<<dim3(nb4), dim3(256), 0, stream>>>(S2, rowp, cs4, dinv, aS2, b2, out, N);
    (void)out_size; (void)ws_size; (void)n_in;
}